// Round 5
// baseline (998.883 us; speedup 1.0000x reference)
//
#include <hip/hip_runtime.h>
#include <stdint.h>

typedef short short8 __attribute__((ext_vector_type(8)));
typedef float f32x4 __attribute__((ext_vector_type(4)));

template<int I> struct IC { static constexpr int value = I; };

__device__ __forceinline__ uint16_t f2bf(float f){
  union{float f;uint32_t u;}v; v.f=f;
  uint32_t u=v.u; u += 0x7fffu + ((u>>16)&1u);
  return (uint16_t)(u>>16);
}
__device__ __forceinline__ float bf2f(uint16_t h){
  union{uint32_t u;float f;}v; v.u=((uint32_t)h)<<16; return v.f;
}

__device__ __forceinline__ void gl_lds16(const void* g, void* l){
  __builtin_amdgcn_global_load_lds((__attribute__((address_space(1))) const void*)g,
                                   (__attribute__((address_space(3))) void*)l, 16, 0, 0);
}

// ---------------- weight prep body (coalesced LDS transpose) ----------------
// out: [kb][tap][f16][lane64][j8] bf16; lane = (co&15)|(ci_oct<<4), j = ci&7
__device__ __forceinline__ void prep_body(const float* __restrict__ w,
                                          const float* __restrict__ s,
                                          uint16_t* __restrict__ dst, int C,
                                          int blk, int tid, float (*lds)[289]){
  const int F16 = C >> 4;
  const int f16 = blk % F16;
  const int kb  = blk / F16;
#pragma unroll
  for (int i = 0; i < 18; ++i){
    int idx = tid + i*256;
    int co  = idx / 288, rem = idx - co*288;
    lds[co][rem] = w[(size_t)(f16*16 + co)*C*9 + (size_t)kb*288 + rem];
  }
  __syncthreads();
  const int lane = tid >> 2;
  const int jj   = (tid & 3)*2;
  const int co_l = lane & 15, oct = lane >> 4;
  const int ci0  = oct*8 + jj;
  const float sc = s[f16*16 + co_l];
  uint32_t* db = (uint32_t*)dst;
#pragma unroll
  for (int tap = 0; tap < 9; ++tap){
    float v0 = lds[co_l][(ci0  )*9 + tap] * sc;
    float v1 = lds[co_l][(ci0+1)*9 + tap] * sc;
    uint32_t pk = (uint32_t)f2bf(v0) | ((uint32_t)f2bf(v1) << 16);
    size_t o = (((size_t)(kb*9 + tap)*F16 + f16)*512 + (size_t)lane*8 + jj) >> 1;
    db[o] = pk;
  }
}

// ---------------- pad body: NCHW fp32 -> padded chunked bf16 [b][kb][Hp][Wp][ci32] swizzled ----------------
template<int C,int H>
__device__ __forceinline__ void pad_body(int idx, const float* __restrict__ x,
                                         uint16_t* __restrict__ xp){
  constexpr int W=H, Hp=H+2, Wp=W+2, KB=C/32;
  int total = 8*KB*Hp*Wp;
  if (idx >= total) return;
  int w = idx % Wp; int t2 = idx / Wp;
  int h = t2 % Hp;  int bk = t2 / Hp;
  const uint32_t key = (uint32_t)((w&7)<<4);
  char* dst = (char*)xp;
  size_t cbyte = (size_t)idx*64;
  if (h==0 || h==Hp-1 || w==0 || w==Wp-1){
    uint4 z = {0,0,0,0};
#pragma unroll
    for (int q=0;q<4;++q) *(uint4*)(dst + ((cbyte + (uint32_t)(q*16)) ^ key)) = z;
  } else {
    const int b = bk/KB, kb = bk - b*KB;
    const float* src = x + (((size_t)(b*C + kb*32)*H + (h-1))*W + (w-1));
#pragma unroll
    for (int q=0;q<4;++q){
      uint16_t tmp[8];
#pragma unroll
      for (int j=0;j<8;++j) tmp[j] = f2bf(src[(size_t)(q*8+j)*(H*W)]);
      *(uint4*)(dst + ((cbyte + (uint32_t)(q*16)) ^ key)) = *(uint4*)tmp;
    }
  }
}

// ---------------- zero border body ----------------
template<int C,int H>
__device__ __forceinline__ void zero_body(int idx, uint16_t* __restrict__ yp){
  constexpr int Hp=H+2, Wp=H+2, KB=C/32;
  constexpr int NB = 2*Wp + 2*(Hp-2);
  int total = 8*KB*NB;
  if (idx >= total) return;
  int j = idx % NB; int bk = idx / NB;
  int h, w;
  if (j < 2*Wp){ h = (j<Wp)?0:(Hp-1); w = j%Wp; }
  else { int j2 = j - 2*Wp; h = 1 + (j2 % (Hp-2)); w = (j2 < (Hp-2))?0:(Wp-1); }
  size_t chunk = ((size_t)bk*Hp + h)*Wp + w;
  const uint32_t key = (uint32_t)((w&7)<<4);
  uint4 z = {0,0,0,0};
  char* dst = (char*)yp;
#pragma unroll
  for (int q=0;q<4;++q) *(uint4*)(dst + ((chunk*64 + (uint32_t)(q*16)) ^ key)) = z;
}

// ---------------- final body: 1x1 conv (5ch) + decode + sigmoid ----------------
template<int C,int H,int OFF,int STRIDE>
__device__ __forceinline__ void final_body(int idx, const uint16_t* __restrict__ y,
    const float* __restrict__ wf, const float* __restrict__ bfp, float* __restrict__ outp)
{
  constexpr int W=H, HW=H*W, KBo=C/32, S=33600;
  if (idx >= 8*HW) return;
  const int b = idx/HW, sp = idx - b*HW;
  const int w = sp % W;
  const uint32_t key = (uint32_t)((w&7)<<4);
  float a0=bfp[0], a1=bfp[1], a2=bfp[2], a3=bfp[3], a4=bfp[4];
  const char* yb = (const char*)y;
  for (int kb=0; kb<KBo; ++kb){
    size_t cbyte = ((size_t)(b*KBo + kb)*HW + sp)*64;
#pragma unroll
    for (int q=0; q<4; ++q){
      uint4 u = *(const uint4*)(yb + ((cbyte + (uint32_t)(q*16)) ^ key));
      const uint16_t* pv = (const uint16_t*)&u;
#pragma unroll
      for (int j=0; j<8; ++j){
        float v = bf2f(pv[j]);
        int ci = kb*32 + q*8 + j;
        a0 += v*wf[0*C+ci]; a1 += v*wf[1*C+ci]; a2 += v*wf[2*C+ci];
        a3 += v*wf[3*C+ci]; a4 += v*wf[4*C+ci];
      }
    }
  }
  const float ax = (float)(sp % W) + 0.5f;
  const float ay = (float)(sp / W) + 0.5f;
  const float o0 = (ax + 0.5f*(a2-a0)) * (float)STRIDE;
  const float o1 = (ay + 0.5f*(a3-a1)) * (float)STRIDE;
  const float o2 = (a0+a2) * (float)STRIDE;
  const float o3 = (a1+a3) * (float)STRIDE;
  const float o4 = 1.0f/(1.0f + expf(-a4));
  float* ob = outp + (size_t)b*5*S + OFF + sp;
  ob[0*S]=o0; ob[1*S]=o1; ob[2*S]=o2; ob[3*S]=o3; ob[4*S]=o4;
}

// ---------------- fused small-kernel wrappers ----------------
__global__ __launch_bounds__(256) void prep_all(
  const float* w15,const float* s15,uint16_t* d15,
  const float* w25,const float* s25,uint16_t* d25,
  const float* w14,const float* s14,uint16_t* d14,
  const float* w24,const float* s24,uint16_t* d24,
  const float* w13,const float* s13,uint16_t* d13,
  const float* w23,const float* s23,uint16_t* d23)
{
  __shared__ float lds[16][289];
  const int b = blockIdx.x, tid = threadIdx.x;
  if      (b <  512) prep_body(w15,s15,d15,512,b      ,tid,lds);
  else if (b < 1024) prep_body(w25,s25,d25,512,b- 512 ,tid,lds);
  else if (b < 1152) prep_body(w14,s14,d14,256,b-1024 ,tid,lds);
  else if (b < 1280) prep_body(w24,s24,d24,256,b-1152 ,tid,lds);
  else if (b < 1312) prep_body(w13,s13,d13,128,b-1280 ,tid,lds);
  else               prep_body(w23,s23,d23,128,b-1312 ,tid,lds);
}

__global__ __launch_bounds__(256) void pad_zero_all(
  const float* x3,const float* x4,const float* x5,
  uint16_t* A3,uint16_t* A4,uint16_t* A5,
  uint16_t* B3,uint16_t* B4,uint16_t* B5)
{
  const int b = blockIdx.x, tid = threadIdx.x;
  if      (b < 3281) pad_body<128,160>((b      )*256+tid, x3, A3);
  else if (b < 4962) pad_body<256, 80>((b-3281)*256+tid, x4, A4);
  else if (b < 5844) pad_body<512, 40>((b-4962)*256+tid, x5, A5);
  else if (b < 5925) zero_body<128,160>((b-5844)*256+tid, B3);
  else if (b < 6006) zero_body<256, 80>((b-5925)*256+tid, B4);
  else               zero_body<512, 40>((b-6006)*256+tid, B5);
}

__global__ __launch_bounds__(256) void final_all(
  const uint16_t* y3,const uint16_t* y4,const uint16_t* y5,
  const float* wf3,const float* bf3,const float* wf4,const float* bf4,
  const float* wf5,const float* bf5, float* out)
{
  const int b = blockIdx.x, tid = threadIdx.x;
  if      (b <  800) final_body<128,160,    0,  8>((b     )*256+tid, y3, wf3, bf3, out);
  else if (b < 1000) final_body<256, 80,25600, 16>((b- 800)*256+tid, y4, wf4, bf4, out);
  else               final_body<512, 40,32000, 32>((b-1000)*256+tid, y5, wf5, bf5, out);
}

// ---------------- 3x3 conv + bias + relu, 16x16x32 MFMA ----------------
// block: 128co x 160sp (TH=4 x TW=40), 4 waves, wave = 64co x 80sp = 4mi x 5ni of 16x16.
// VGPR ~84, LDS 2x16128 -> 4 blocks/CU (16 waves, 50% occupancy).
template<int C,int H,bool PADOUT>
__device__ __forceinline__ void conv_body(int lbid,
    const uint16_t* __restrict__ in, const uint16_t* __restrict__ wq,
    const float* __restrict__ bias, uint16_t* __restrict__ out, char* lds)
{
  constexpr int W=H, Hp=H+2, Wp=W+2, KB=C/32, TW=40, TH=4;
  constexpr int COB=128, F16B=C/16;
  constexpr int R=TH+2, ROWB=42*64, BUF=R*ROWB, NT=R*3, WAVES=4;
  constexpr int TAPSTRIDE = F16B*1024;
  const int tid = threadIdx.x, lane = tid&63, wave = tid>>6;
  const int wm = wave>>1, wn = wave&1;
  const int l15 = lane&15, h2 = lane>>4;

  int t = lbid;
  const int cb = t % (C/COB); t /= (C/COB);
  const int wt = t % (W/TW);  t /= (W/TW);
  const int ht = t % (H/TH);
  const int b  = t / (H/TH);
  const int h0 = ht*TH, w0 = wt*TW;

  int addrB[5][3];
#pragma unroll
  for (int ni=0; ni<5; ++ni){
    int s = wn*80 + ni*16 + l15;
    int th = s/40, tw = s - th*40;
#pragma unroll
    for (int dw=0; dw<3; ++dw){
      int col = tw + dw;
      addrB[ni][dw] = th*ROWB + ((col*64 + h2*16) ^ ((col&7)<<4));
    }
  }

  const char* wp = (const char*)wq + (size_t)(cb*8 + wm*4)*1024 + (size_t)lane*16;

  f32x4 acc[4][5];
#pragma unroll
  for (int mi=0;mi<4;++mi)
#pragma unroll
    for (int ni=0;ni<5;++ni)
      acc[mi][ni] = (f32x4){0.f,0.f,0.f,0.f};

  short8 a_[4];
#pragma unroll
  for (int mi=0; mi<4; ++mi) a_[mi] = *(const short8*)(wp + mi*1024);
  wp += TAPSTRIDE;

  auto STAGE = [&](int bi, int kb){
    const char* src = (const char*)(in + ((size_t)(b*KB + kb)*Hp + h0)*((size_t)Wp*32) + (size_t)w0*32);
    for (int tt = wave; tt < NT; tt += WAVES){
      int r = tt/3, k = tt - r*3;
      char* l = lds + bi*BUF + r*ROWB + k*1024;
      const char* g = src + (size_t)r*(Wp*64) + k*1024 + lane*16;
      if (k < 2 || lane < 40) gl_lds16(g, l);
    }
  };

  auto COMPUTE = [&](auto BC){
    constexpr int BI = decltype(BC)::value;
    const char* lb = lds + BI*BUF;
#pragma unroll
    for (int tap=0; tap<9; ++tap){
      const int dh = tap/3, dw = tap - dh*3;
      short8 an_[4];
#pragma unroll
      for (int mi=0;mi<4;++mi) an_[mi] = *(const short8*)(wp + mi*1024);
      wp += TAPSTRIDE;
      short8 bf[5];
#pragma unroll
      for (int ni=0; ni<5; ++ni)
        bf[ni] = *(const short8*)(lb + addrB[ni][dw] + dh*ROWB);
#pragma unroll
      for (int ni=0; ni<5; ++ni)
#pragma unroll
        for (int mi=0; mi<4; ++mi)
          acc[mi][ni] = __builtin_amdgcn_mfma_f32_16x16x32_bf16(a_[mi], bf[ni], acc[mi][ni], 0,0,0);
#pragma unroll
      for (int mi=0;mi<4;++mi) a_[mi] = an_[mi];
    }
  };

  STAGE(0, 0);
  __syncthreads();
#pragma unroll 1
  for (int kb = 0; kb < KB; kb += 2){
    STAGE(1, kb+1);
    COMPUTE(IC<0>{});
    __syncthreads();
    if (kb+2 < KB) STAGE(0, kb+2);
    COMPUTE(IC<1>{});
    __syncthreads();
  }

#pragma unroll
  for (int mi=0; mi<4; ++mi){
    const int kbo = cb*4 + wm*2 + (mi>>1);
    const int cobase = kbo*32 + (mi&1)*16 + h2*4;
    const f32x4 bv = *(const f32x4*)(bias + cobase);
#pragma unroll
    for (int ni=0; ni<5; ++ni){
      const int s = wn*80 + ni*16 + l15;
      const int th = s/40, tw = s - th*40;
      size_t chunk; uint32_t key;
      if (PADOUT){
        const int hh = h0+th+1, ww = w0+tw+1;
        chunk = ((size_t)(b*KB + kbo)*Hp + hh)*Wp + ww;
        key = (uint32_t)((ww&7)<<4);
      } else {
        const int hh = h0+th, ww = w0+tw;
        chunk = ((size_t)(b*KB + kbo)*H + hh)*W + ww;
        key = (uint32_t)((ww&7)<<4);
      }
      float v0 = fmaxf(acc[mi][ni][0] + bv[0], 0.f);
      float v1 = fmaxf(acc[mi][ni][1] + bv[1], 0.f);
      float v2 = fmaxf(acc[mi][ni][2] + bv[2], 0.f);
      float v3 = fmaxf(acc[mi][ni][3] + bv[3], 0.f);
      uint2 dd;
      dd.x = (uint32_t)f2bf(v0) | ((uint32_t)f2bf(v1)<<16);
      dd.y = (uint32_t)f2bf(v2) | ((uint32_t)f2bf(v3)<<16);
      *(uint2*)((char*)out + ((chunk*64 + (uint32_t)((mi&1)*32 + h2*8)) ^ key)) = dd;
    }
  }
}

template<bool PADOUT>
__global__ __launch_bounds__(256, 4) void conv_all(int b45, int b34,
    const uint16_t* in5, const uint16_t* wq5, const float* bi5, uint16_t* o5,
    const uint16_t* in4, const uint16_t* wq4, const float* bi4, uint16_t* o4,
    const uint16_t* in3, const uint16_t* wq3, const float* bi3, uint16_t* o3)
{
  __shared__ __align__(16) char lds[2*6*2688];
  const int bid = blockIdx.x;
  if (bid < b45)      conv_body<512, 40, PADOUT>(bid,       in5, wq5, bi5, o5, lds);
  else if (bid < b34) conv_body<256, 80, PADOUT>(bid - b45, in4, wq4, bi4, o4, lds);
  else                conv_body<128,160, PADOUT>(bid - b34, in3, wq3, bi3, o3, lds);
}

// ---------------- per-head fallback wrappers (sequential path) ----------------
__global__ __launch_bounds__(256) void prep_one(const float* w, const float* s,
                                                uint16_t* dst, int C){
  __shared__ float lds[16][289];
  prep_body(w, s, dst, C, blockIdx.x, threadIdx.x, lds);
}
template<int C,int H>
__global__ __launch_bounds__(256) void pad_one(const float* x, uint16_t* xp){
  pad_body<C,H>(blockIdx.x*256 + threadIdx.x, x, xp);
}
template<int C,int H>
__global__ __launch_bounds__(256) void zero_one(uint16_t* yp){
  zero_body<C,H>(blockIdx.x*256 + threadIdx.x, yp);
}
template<int C,int H,int OFF,int STRIDE>
__global__ __launch_bounds__(256) void final_one(const uint16_t* y, const float* wf,
                                                 const float* bfp, float* out){
  final_body<C,H,OFF,STRIDE>(blockIdx.x*256 + threadIdx.x, y, wf, bfp, out);
}

extern "C" void kernel_launch(void* const* d_in, const int* in_sizes, int n_in,
                              void* d_out, int out_size, void* d_ws, size_t ws_size,
                              hipStream_t stream){
  (void)in_sizes; (void)n_in; (void)out_size;
  const float* x[3] = {(const float*)d_in[0], (const float*)d_in[1], (const float*)d_in[2]};
  const float *w1[3],*s1[3],*b1[3],*w2[3],*s2[3],*b2[3],*wf[3],*bfp[3];
  for (int h=0; h<3; ++h){
    const int base = 3 + h*8;
    w1[h]=(const float*)d_in[base+0]; s1[h]=(const float*)d_in[base+1];
    b1[h]=(const float*)d_in[base+2]; w2[h]=(const float*)d_in[base+3];
    s2[h]=(const float*)d_in[base+4]; b2[h]=(const float*)d_in[base+5];
    wf[h]=(const float*)d_in[base+6]; bfp[h]=(const float*)d_in[base+7];
  }
  // h: 0=p3(C128,H160), 1=p4(C256,H80), 2=p5(C512,H40)
  static const int   Cs[3] = {128, 256, 512};
  static const size_t Wb[3] = {294912, 1179648, 4718592};
  static const size_t Ab[3] = {53747712, 27541504, 14450688};
  static const int   NB[3] = {1280, 640, 320};
  float* out = (float*)d_out;
  char* ws = (char*)d_ws;

  size_t off = 0; size_t wOff[3][2];
  for (int h=0; h<3; ++h) for (int c=0; c<2; ++c){ wOff[h][c]=off; off += Wb[h]; }
  off = (off + 255) & ~(size_t)255;
  size_t aOff[3], bOff[3];
  for (int h=0; h<3; ++h){ aOff[h]=off; off += Ab[h]; }
  for (int h=0; h<3; ++h){ bOff[h]=off; off += Ab[h]; }
  const size_t fusedNeed = off;

  const size_t seqA = (2*4718592 + 255) & ~(size_t)255;
  const size_t seqB = seqA + 53747712;
  const size_t seqNeed = seqB + 53747712;

  if (ws_size >= fusedNeed){
    prep_all<<<1344, 256, 0, stream>>>(
      w1[2], s1[2], (uint16_t*)(ws+wOff[2][0]),
      w2[2], s2[2], (uint16_t*)(ws+wOff[2][1]),
      w1[1], s1[1], (uint16_t*)(ws+wOff[1][0]),
      w2[1], s2[1], (uint16_t*)(ws+wOff[1][1]),
      w1[0], s1[0], (uint16_t*)(ws+wOff[0][0]),
      w2[0], s2[0], (uint16_t*)(ws+wOff[0][1]));
    pad_zero_all<<<6088, 256, 0, stream>>>(
      x[0], x[1], x[2],
      (uint16_t*)(ws+aOff[0]), (uint16_t*)(ws+aOff[1]), (uint16_t*)(ws+aOff[2]),
      (uint16_t*)(ws+bOff[0]), (uint16_t*)(ws+bOff[1]), (uint16_t*)(ws+bOff[2]));
    const int b45 = NB[2], b34 = NB[2]+NB[1], grid = NB[2]+NB[1]+NB[0];
    conv_all<true><<<grid, 256, 0, stream>>>(b45, b34,
      (const uint16_t*)(ws+aOff[2]), (const uint16_t*)(ws+wOff[2][0]), b1[2], (uint16_t*)(ws+bOff[2]),
      (const uint16_t*)(ws+aOff[1]), (const uint16_t*)(ws+wOff[1][0]), b1[1], (uint16_t*)(ws+bOff[1]),
      (const uint16_t*)(ws+aOff[0]), (const uint16_t*)(ws+wOff[0][0]), b1[0], (uint16_t*)(ws+bOff[0]));
    conv_all<false><<<grid, 256, 0, stream>>>(b45, b34,
      (const uint16_t*)(ws+bOff[2]), (const uint16_t*)(ws+wOff[2][1]), b2[2], (uint16_t*)(ws+aOff[2]),
      (const uint16_t*)(ws+bOff[1]), (const uint16_t*)(ws+wOff[1][1]), b2[1], (uint16_t*)(ws+aOff[1]),
      (const uint16_t*)(ws+bOff[0]), (const uint16_t*)(ws+wOff[0][1]), b2[0], (uint16_t*)(ws+aOff[0]));
    final_all<<<1050, 256, 0, stream>>>(
      (const uint16_t*)(ws+aOff[0]), (const uint16_t*)(ws+aOff[1]), (const uint16_t*)(ws+aOff[2]),
      wf[0], bfp[0], wf[1], bfp[1], wf[2], bfp[2], out);
  } else {
    if (ws_size < seqNeed) return;
    uint16_t* W1p = (uint16_t*)(ws + 0);
    uint16_t* W2p = (uint16_t*)(ws + 4718592);
    uint16_t* A   = (uint16_t*)(ws + seqA);
    uint16_t* B   = (uint16_t*)(ws + seqB);
    for (int h=0; h<3; ++h){
      int blocks = (Cs[h]/32)*(Cs[h]/16);
      prep_one<<<blocks, 256, 0, stream>>>(w1[h], s1[h], W1p, Cs[h]);
      prep_one<<<blocks, 256, 0, stream>>>(w2[h], s2[h], W2p, Cs[h]);
      int grid = NB[h];
      int b45, b34;
      if (h==2){ b45=grid; b34=grid; } else if (h==1){ b45=0; b34=grid; } else { b45=0; b34=0; }
      if (h==0){
        pad_one<128,160><<<3281,256,0,stream>>>(x[0], A);
        zero_one<128,160><<<81,256,0,stream>>>(B);
      } else if (h==1){
        pad_one<256,80><<<1681,256,0,stream>>>(x[1], A);
        zero_one<256,80><<<81,256,0,stream>>>(B);
      } else {
        pad_one<512,40><<<882,256,0,stream>>>(x[2], A);
        zero_one<512,40><<<82,256,0,stream>>>(B);
      }
      conv_all<true><<<grid, 256, 0, stream>>>(b45, b34,
        A, W1p, b1[h], B,  A, W1p, b1[h], B,  A, W1p, b1[h], B);
      conv_all<false><<<grid, 256, 0, stream>>>(b45, b34,
        B, W2p, b2[h], A,  B, W2p, b2[h], A,  B, W2p, b2[h], A);
      if (h==0)      final_one<128,160,     0,  8><<<800,256,0,stream>>>(A, wf[0], bfp[0], out);
      else if (h==1) final_one<256, 80, 25600, 16><<<200,256,0,stream>>>(A, wf[1], bfp[1], out);
      else           final_one<512, 40, 32000, 32><<< 50,256,0,stream>>>(A, wf[2], bfp[2], out);
    }
  }
}